// Round 10
// baseline (665.611 us; speedup 1.0000x reference)
//
#include <hip/hip_runtime.h>

#define NSEG 4096
#define QSCALE 131072.0f          // 2^17 fixed-point scale
#define QINV   (1.0f / 131072.0f)
#define NB 512                    // blocks (= partial count)
#define DIAG_REP 4

typedef unsigned long long u64;
typedef unsigned int u32;
typedef float f32x4 __attribute__((ext_vector_type(4)));
typedef float f32x2 __attribute__((ext_vector_type(2)));

__device__ __forceinline__ u64 packexp(float x, float y) {
    u32 lo = __float2uint_rn(__expf(x) * QSCALE);
    u32 hi = __float2uint_rn(__expf(y) * QSCALE);
    return (u64)lo | ((u64)hi << 32);
}

// ---------------------------------------------------------------------------
// DIAG 1: full loads + full VALU (exp/pack), NO atomics. 64KB LDS dummy pins
// occupancy to 2 blocks/CU (same as real reduce). REP x over the data.
// ---------------------------------------------------------------------------
__global__ __launch_bounds__(1024) void diag_load(
    const f32x4* __restrict__ xab4, const f32x4* __restrict__ xba4,
    const int2* __restrict__ src2, const int2* __restrict__ tar2,
    float* __restrict__ sink, int Eh)
{
    __shared__ u64 dummy[2 * NSEG];          // occupancy pin only
    dummy[threadIdx.x] = 0ull;
    __syncthreads();

    const int stride = gridDim.x * 1024;
    int acc = 0;
    for (int rep = 0; rep < DIAG_REP; ++rep) {
        for (int u = blockIdx.x * 1024 + threadIdx.x; u < Eh; u += stride) {
            f32x4 a = xab4[u];
            f32x4 b = xba4[u];
            int2 s = src2[u];
            int2 t = tar2[u];
            u64 p0 = packexp(a.x, a.y), p1 = packexp(a.z, a.w);
            u64 p2 = packexp(b.x, b.y), p3 = packexp(b.z, b.w);
            asm volatile("" :: "v"(p0), "v"(p1), "v"(p2), "v"(p3));
            acc += s.x + s.y + t.x + t.y;
        }
    }
    asm volatile("" :: "v"(acc));
    acc += (int)dummy[threadIdx.x];
    if (threadIdx.x == 1024 + acc * 0)       // never true; keeps acc live
        sink[blockIdx.x] = (float)acc;
    if (threadIdx.x == 0) sink[blockIdx.x] = (float)acc;   // rewritten by reduce
}

// ---------------------------------------------------------------------------
// DIAG 2: index loads only + 4 scattered u64 LDS atomics (constant payload).
// Isolates the scattered DS-atomic path at real-reduce occupancy.
// ---------------------------------------------------------------------------
__global__ __launch_bounds__(1024) void diag_atom(
    const int2* __restrict__ src2, const int2* __restrict__ tar2,
    float* __restrict__ sink, int Eh)
{
    __shared__ u64 ls[2 * NSEG];
    for (int i = threadIdx.x; i < 2 * NSEG; i += 1024) ls[i] = 0ull;
    __syncthreads();

    const int stride = gridDim.x * 1024;
    const u64 K = 0x0000000100000001ull;
    for (int rep = 0; rep < DIAG_REP; ++rep) {
        for (int u = blockIdx.x * 1024 + threadIdx.x; u < Eh; u += stride) {
            int2 s = src2[u];
            int2 t = tar2[u];
            atomicAdd(&ls[s.x], K);
            atomicAdd(&ls[s.y], K);
            atomicAdd(&ls[NSEG + t.x], K);
            atomicAdd(&ls[NSEG + t.y], K);
        }
    }
    __syncthreads();

    // flush so nothing is removable; region rewritten by the real reduce
    f32x2* dst = (f32x2*)(sink + (size_t)blockIdx.x * (4 * NSEG));
    for (int i = threadIdx.x; i < 2 * NSEG; i += 1024) {
        u64 v = ls[i];
        f32x2 w = { (float)(u32)v, (float)(u32)(v >> 32) };
        dst[i] = w;
    }
}

// ===========================================================================
// Real pipeline — EXACT R5 structure (357 µs reference).
// ===========================================================================
__global__ __launch_bounds__(1024) void dsp_reduce(
    const f32x4* __restrict__ xab4, const f32x4* __restrict__ xba4,
    const int2* __restrict__ src2, const int2* __restrict__ tar2,
    float* __restrict__ partials, float* __restrict__ gtab, int Eh)
{
    __shared__ u64 ls[2 * NSEG];
    for (int i = threadIdx.x; i < 2 * NSEG; i += 1024) ls[i] = 0ull;
    __syncthreads();

    const int stride = gridDim.x * 1024;
    int u = blockIdx.x * 1024 + threadIdx.x;

    f32x4 a, b; int2 s, t;
    if (u < Eh) { a = xab4[u]; b = xba4[u]; s = src2[u]; t = tar2[u]; }

    while (u < Eh) {
        int un = u + stride;
        f32x4 an, bn; int2 sn, tn;
        if (un < Eh) { an = xab4[un]; bn = xba4[un]; sn = src2[un]; tn = tar2[un]; }

        atomicAdd(&ls[s.x], packexp(a.x, a.y));
        atomicAdd(&ls[s.y], packexp(a.z, a.w));
        atomicAdd(&ls[NSEG + t.x], packexp(b.x, b.y));
        atomicAdd(&ls[NSEG + t.y], packexp(b.z, b.w));

        u = un; a = an; b = bn; s = sn; t = tn;
    }
    __syncthreads();

    if (partials) {
        f32x2* dst = (f32x2*)(partials + (size_t)blockIdx.x * (4 * NSEG));
        for (int i = threadIdx.x; i < 2 * NSEG; i += 1024) {
            u64 v = ls[i];
            f32x2 w = { (float)(u32)v * QINV, (float)(u32)(v >> 32) * QINV };
            dst[i] = w;
        }
    } else {
        for (int i = threadIdx.x; i < 2 * NSEG; i += 1024) {
            u64 v = ls[i];
            float lo = (float)(u32)v * QINV;
            float hi = (float)(u32)(v >> 32) * QINV;
            if (lo != 0.f) atomicAdd(&gtab[2 * i], lo);
            if (hi != 0.f) atomicAdd(&gtab[2 * i + 1], hi);
        }
    }
}

__global__ __launch_bounds__(256) void dsp_sum(
    const f32x4* __restrict__ partials, f32x4* __restrict__ rcp_out, int nb)
{
    int i = blockIdx.x * blockDim.x + threadIdx.x;
    f32x4 acc = {0.f, 0.f, 0.f, 0.f};
    for (int p = 0; p < nb; ++p)
        acc += __builtin_nontemporal_load(&partials[(size_t)p * NSEG + i]);
    f32x4 r;
    r.x = (acc.x > 0.f) ? 1.f / acc.x : 0.f;
    r.y = (acc.y > 0.f) ? 1.f / acc.y : 0.f;
    r.z = (acc.z > 0.f) ? 1.f / acc.z : 0.f;
    r.w = (acc.w > 0.f) ? 1.f / acc.w : 0.f;
    rcp_out[i] = r;
}

__global__ void dsp_rcp(float* __restrict__ sums, int n)
{
    int i = blockIdx.x * blockDim.x + threadIdx.x;
    if (i < n) {
        float v = sums[i];
        sums[i] = (v > 0.f) ? 1.f / v : 0.f;
    }
}

__global__ __launch_bounds__(1024) void dsp_norm(
    const f32x4* __restrict__ xab4, const f32x4* __restrict__ xba4,
    const int2* __restrict__ src2, const int2* __restrict__ tar2,
    const f32x4* __restrict__ rcp_tab,
    f32x4* __restrict__ out, int Eh)
{
    __shared__ float ls[4 * NSEG];
    for (int i = threadIdx.x; i < NSEG; i += 1024)
        ((f32x4*)ls)[i] = rcp_tab[i];
    __syncthreads();

    const int stride = gridDim.x * 1024;
    int u = blockIdx.x * 1024 + threadIdx.x;

    f32x4 a, b; int2 s, t;
    if (u < Eh) { a = xab4[u]; b = xba4[u]; s = src2[u]; t = tar2[u]; }

    while (u < Eh) {
        int un = u + stride;
        f32x4 an, bn; int2 sn, tn;
        if (un < Eh) { an = xab4[un]; bn = xba4[un]; sn = src2[un]; tn = tar2[un]; }

        f32x2 ra0 = *(const f32x2*)&ls[2 * s.x];
        f32x2 ra1 = *(const f32x2*)&ls[2 * s.y];
        f32x2 rb0 = *(const f32x2*)&ls[2 * NSEG + 2 * t.x];
        f32x2 rb1 = *(const f32x2*)&ls[2 * NSEG + 2 * t.y];

        f32x4 zab = { __expf(a.x) * ra0.x, __expf(a.y) * ra0.y,
                      __expf(a.z) * ra1.x, __expf(a.w) * ra1.y };
        f32x4 zba = { __expf(b.x) * rb0.x, __expf(b.y) * rb0.y,
                      __expf(b.z) * rb1.x, __expf(b.w) * rb1.y };
        f32x4 prod = zab * zba;

        __builtin_nontemporal_store(prod, &out[u]);
        __builtin_nontemporal_store(zab,  &out[Eh + u]);
        __builtin_nontemporal_store(zba,  &out[2 * Eh + u]);

        u = un; a = an; b = bn; s = sn; t = tn;
    }
}

extern "C" void kernel_launch(void* const* d_in, const int* in_sizes, int n_in,
                              void* d_out, int out_size, void* d_ws, size_t ws_size,
                              hipStream_t stream)
{
    const int E  = in_sizes[0] / 2;
    const int Eh = E / 2;
    const f32x4* xab4 = (const f32x4*)d_in[0];
    const f32x4* xba4 = (const f32x4*)d_in[1];
    const int2*  src2 = (const int2*)d_in[2];
    const int2*  tar2 = (const int2*)d_in[3];

    float* rcp_tab  = (float*)d_ws;           // 16384 floats
    float* partials = (float*)((char*)d_ws + 65536);
    size_t need = 65536 + (size_t)NB * 65536;

    if (ws_size >= need) {
        // ---- diagnostics (results overwritten by the real pipeline) ----
        diag_load<<<NB, 1024, 0, stream>>>(xab4, xba4, src2, tar2, partials, Eh);
        diag_atom<<<NB, 1024, 0, stream>>>(src2, tar2, partials, Eh);

        // ---- real pipeline (R5 reference structure) ----
        dsp_reduce<<<NB, 1024, 0, stream>>>(xab4, xba4, src2, tar2,
                                            partials, nullptr, Eh);
        dsp_sum<<<NSEG / 256, 256, 0, stream>>>((const f32x4*)partials,
                                                (f32x4*)rcp_tab, NB);
    } else {
        (void)hipMemsetAsync(d_ws, 0, 65536, stream);
        dsp_reduce<<<NB, 1024, 0, stream>>>(xab4, xba4, src2, tar2,
                                            nullptr, rcp_tab, Eh);
        dsp_rcp<<<64, 256, 0, stream>>>(rcp_tab, 4 * NSEG);
    }

    dsp_norm<<<NB, 1024, 0, stream>>>(xab4, xba4, src2, tar2,
                                      (const f32x4*)rcp_tab,
                                      (f32x4*)d_out, Eh);
}

// Round 11
// 410.082 us; speedup vs baseline: 1.6231x; 1.6231x over previous
//
#include <hip/hip_runtime.h>
#include <hip/hip_fp16.h>

#define NSEG 4096
#define QSCALE 131072.0f          // 2^17 fixed-point scale
#define QINV   (1.0f / 131072.0f)
#define NB 512                    // blocks (= partial count)

typedef unsigned long long u64;
typedef unsigned int u32;
typedef unsigned short u16;
typedef float f32x4 __attribute__((ext_vector_type(4)));
typedef float f32x2 __attribute__((ext_vector_type(2)));
typedef u64 u64x2 __attribute__((ext_vector_type(2)));

__device__ __forceinline__ u64 packexp(float x, float y) {
    u32 lo = __float2uint_rn(__expf(x) * QSCALE);
    u32 hi = __float2uint_rn(__expf(y) * QSCALE);
    return (u64)lo | ((u64)hi << 32);
}

// pack exp of 4 floats as 4 f16 into one u64: (x,y) -> lo32, (z,w) -> hi32
__device__ __forceinline__ u64 pack4h(f32x4 v) {
    u32 lo = ((u32)__half_as_ushort(__float2half(__expf(v.y))) << 16)
           |  (u32)__half_as_ushort(__float2half(__expf(v.x)));
    u32 hi = ((u32)__half_as_ushort(__float2half(__expf(v.w))) << 16)
           |  (u32)__half_as_ushort(__float2half(__expf(v.z)));
    return (u64)lo | ((u64)hi << 32);
}

// unpack 2 f16 from u32 -> fixed-point-packed u64
__device__ __forceinline__ u64 h2fixed(u32 h) {
    float e0 = __half2float(__ushort_as_half((u16)h));
    float e1 = __half2float(__ushort_as_half((u16)(h >> 16)));
    u32 lo = __float2uint_rn(e0 * QSCALE);
    u32 hi = __float2uint_rn(e1 * QSCALE);
    return (u64)lo | ((u64)hi << 32);
}

// ---------------------------------------------------------------------------
// Pass 1a: PURE STREAMING — exp + f16-pack, no LDS, no atomics.
// (diag_load structure, proven ~70 µs/pass.) Normal store keeps packed
// array L3-resident for pass 1b.
// ---------------------------------------------------------------------------
__global__ __launch_bounds__(1024) void dsp_exp(
    const f32x4* __restrict__ xab4, const f32x4* __restrict__ xba4,
    u64x2* __restrict__ packed, int Eh)
{
    const int stride = gridDim.x * 1024;
    for (int u = blockIdx.x * 1024 + threadIdx.x; u < Eh; u += stride) {
        f32x4 a = xab4[u];
        f32x4 b = xba4[u];
        u64x2 w = { pack4h(a), pack4h(b) };
        packed[u] = w;
    }
}

// ---------------------------------------------------------------------------
// Pass 1b: SCATTER ONLY — read packed exps (L3-warm) + indices, convert to
// fixed point, u64 LDS atomics. (diag_atom structure, proven ~6.5 µs/pass
// for the atomic part.)
// ---------------------------------------------------------------------------
__global__ __launch_bounds__(1024) void dsp_scatter(
    const u64x2* __restrict__ packed,
    const int2* __restrict__ src2, const int2* __restrict__ tar2,
    float* __restrict__ partials, int Eh)
{
    __shared__ u64 ls[2 * NSEG];    // ab at [0,4096), ba at [4096,8192)
    for (int i = threadIdx.x; i < 2 * NSEG; i += 1024) ls[i] = 0ull;
    __syncthreads();

    const int stride = gridDim.x * 1024;
    for (int u = blockIdx.x * 1024 + threadIdx.x; u < Eh; u += stride) {
        u64x2 p = packed[u];
        int2 s = src2[u];
        int2 t = tar2[u];

        atomicAdd(&ls[s.x],        h2fixed((u32)p.x));
        atomicAdd(&ls[s.y],        h2fixed((u32)(p.x >> 32)));
        atomicAdd(&ls[NSEG + t.x], h2fixed((u32)p.y));
        atomicAdd(&ls[NSEG + t.y], h2fixed((u32)(p.y >> 32)));
    }
    __syncthreads();

    f32x2* dst = (f32x2*)(partials + (size_t)blockIdx.x * (4 * NSEG));
    for (int i = threadIdx.x; i < 2 * NSEG; i += 1024) {
        u64 v = ls[i];
        f32x2 w = { (float)(u32)v * QINV, (float)(u32)(v >> 32) * QINV };
        dst[i] = w;
    }
}

// ---------------------------------------------------------------------------
// Pass 2: column-sum NB partial tables, store reciprocals. (R5 verbatim)
// ---------------------------------------------------------------------------
__global__ __launch_bounds__(256) void dsp_sum(
    const f32x4* __restrict__ partials, f32x4* __restrict__ rcp_out, int nb)
{
    int i = blockIdx.x * blockDim.x + threadIdx.x;   // 0..4095
    f32x4 acc = {0.f, 0.f, 0.f, 0.f};
    for (int p = 0; p < nb; ++p)
        acc += __builtin_nontemporal_load(&partials[(size_t)p * NSEG + i]);
    f32x4 r;
    r.x = (acc.x > 0.f) ? 1.f / acc.x : 0.f;
    r.y = (acc.y > 0.f) ? 1.f / acc.y : 0.f;
    r.z = (acc.z > 0.f) ? 1.f / acc.z : 0.f;
    r.w = (acc.w > 0.f) ? 1.f / acc.w : 0.f;
    rcp_out[i] = r;
}

// ---------------------------------------------------------------------------
// Fallback single-kernel reduce (R5-proven, 170 µs) for small ws.
// ---------------------------------------------------------------------------
__global__ __launch_bounds__(1024) void dsp_reduce(
    const f32x4* __restrict__ xab4, const f32x4* __restrict__ xba4,
    const int2* __restrict__ src2, const int2* __restrict__ tar2,
    float* __restrict__ partials, float* __restrict__ gtab, int Eh)
{
    __shared__ u64 ls[2 * NSEG];
    for (int i = threadIdx.x; i < 2 * NSEG; i += 1024) ls[i] = 0ull;
    __syncthreads();

    const int stride = gridDim.x * 1024;
    for (int u = blockIdx.x * 1024 + threadIdx.x; u < Eh; u += stride) {
        f32x4 a = xab4[u]; f32x4 b = xba4[u];
        int2 s = src2[u]; int2 t = tar2[u];
        atomicAdd(&ls[s.x], packexp(a.x, a.y));
        atomicAdd(&ls[s.y], packexp(a.z, a.w));
        atomicAdd(&ls[NSEG + t.x], packexp(b.x, b.y));
        atomicAdd(&ls[NSEG + t.y], packexp(b.z, b.w));
    }
    __syncthreads();

    if (partials) {
        f32x2* dst = (f32x2*)(partials + (size_t)blockIdx.x * (4 * NSEG));
        for (int i = threadIdx.x; i < 2 * NSEG; i += 1024) {
            u64 v = ls[i];
            f32x2 w = { (float)(u32)v * QINV, (float)(u32)(v >> 32) * QINV };
            dst[i] = w;
        }
    } else {
        for (int i = threadIdx.x; i < 2 * NSEG; i += 1024) {
            u64 v = ls[i];
            float lo = (float)(u32)v * QINV;
            float hi = (float)(u32)(v >> 32) * QINV;
            if (lo != 0.f) atomicAdd(&gtab[2 * i], lo);
            if (hi != 0.f) atomicAdd(&gtab[2 * i + 1], hi);
        }
    }
}

__global__ void dsp_rcp(float* __restrict__ sums, int n)
{
    int i = blockIdx.x * blockDim.x + threadIdx.x;
    if (i < n) {
        float v = sums[i];
        sums[i] = (v > 0.f) ? 1.f / v : 0.f;
    }
}

// ---------------------------------------------------------------------------
// Pass 3: normalize + 3 outputs. (R5 verbatim: LDS rcp tables, 1-deep
// prefetch, NT stores.)
// ---------------------------------------------------------------------------
__global__ __launch_bounds__(1024) void dsp_norm(
    const f32x4* __restrict__ xab4, const f32x4* __restrict__ xba4,
    const int2* __restrict__ src2, const int2* __restrict__ tar2,
    const f32x4* __restrict__ rcp_tab,
    f32x4* __restrict__ out, int Eh)
{
    __shared__ float ls[4 * NSEG];
    for (int i = threadIdx.x; i < NSEG; i += 1024)
        ((f32x4*)ls)[i] = rcp_tab[i];
    __syncthreads();

    const int stride = gridDim.x * 1024;
    int u = blockIdx.x * 1024 + threadIdx.x;

    f32x4 a, b; int2 s, t;
    if (u < Eh) { a = xab4[u]; b = xba4[u]; s = src2[u]; t = tar2[u]; }

    while (u < Eh) {
        int un = u + stride;
        f32x4 an, bn; int2 sn, tn;
        if (un < Eh) { an = xab4[un]; bn = xba4[un]; sn = src2[un]; tn = tar2[un]; }

        f32x2 ra0 = *(const f32x2*)&ls[2 * s.x];
        f32x2 ra1 = *(const f32x2*)&ls[2 * s.y];
        f32x2 rb0 = *(const f32x2*)&ls[2 * NSEG + 2 * t.x];
        f32x2 rb1 = *(const f32x2*)&ls[2 * NSEG + 2 * t.y];

        f32x4 zab = { __expf(a.x) * ra0.x, __expf(a.y) * ra0.y,
                      __expf(a.z) * ra1.x, __expf(a.w) * ra1.y };
        f32x4 zba = { __expf(b.x) * rb0.x, __expf(b.y) * rb0.y,
                      __expf(b.z) * rb1.x, __expf(b.w) * rb1.y };
        f32x4 prod = zab * zba;

        __builtin_nontemporal_store(prod, &out[u]);            // zab*zba
        __builtin_nontemporal_store(zab,  &out[Eh + u]);       // zab
        __builtin_nontemporal_store(zba,  &out[2 * Eh + u]);   // zba

        u = un; a = an; b = bn; s = sn; t = tn;
    }
}

extern "C" void kernel_launch(void* const* d_in, const int* in_sizes, int n_in,
                              void* d_out, int out_size, void* d_ws, size_t ws_size,
                              hipStream_t stream)
{
    const int E  = in_sizes[0] / 2;
    const int Eh = E / 2;
    const f32x4* xab4 = (const f32x4*)d_in[0];
    const f32x4* xba4 = (const f32x4*)d_in[1];
    const int2*  src2 = (const int2*)d_in[2];
    const int2*  tar2 = (const int2*)d_in[3];

    // ws layout: rcp f32[16384] (64KB) | partials NB*64KB (32MB) | packed 16B*Eh
    float* rcp_tab  = (float*)d_ws;
    float* partials = (float*)((char*)d_ws + 65536);
    u64x2* packed   = (u64x2*)((char*)d_ws + 65536 + (size_t)NB * 65536);
    size_t need_split = 65536 + (size_t)NB * 65536 + (size_t)Eh * 16;
    size_t need_r5    = 65536 + (size_t)NB * 65536;

    if (ws_size >= need_split) {
        dsp_exp<<<NB, 1024, 0, stream>>>(xab4, xba4, packed, Eh);
        dsp_scatter<<<NB, 1024, 0, stream>>>(packed, src2, tar2, partials, Eh);
        dsp_sum<<<NSEG / 256, 256, 0, stream>>>((const f32x4*)partials,
                                                (f32x4*)rcp_tab, NB);
    } else if (ws_size >= need_r5) {
        dsp_reduce<<<NB, 1024, 0, stream>>>(xab4, xba4, src2, tar2,
                                            partials, nullptr, Eh);
        dsp_sum<<<NSEG / 256, 256, 0, stream>>>((const f32x4*)partials,
                                                (f32x4*)rcp_tab, NB);
    } else {
        (void)hipMemsetAsync(d_ws, 0, 65536, stream);
        dsp_reduce<<<NB, 1024, 0, stream>>>(xab4, xba4, src2, tar2,
                                            nullptr, rcp_tab, Eh);
        dsp_rcp<<<64, 256, 0, stream>>>(rcp_tab, 4 * NSEG);
    }

    dsp_norm<<<NB, 1024, 0, stream>>>(xab4, xba4, src2, tar2,
                                      (const f32x4*)rcp_tab,
                                      (f32x4*)d_out, Eh);
}